// Round 14
// baseline (96.444 us; speedup 1.0000x reference)
//
#include <hip/hip_runtime.h>
#include <hip/hip_bf16.h>

#define N_TOK  1728     // 12*12*12
#define CDIM   64
#define NHEADS 32       // head_dim = 2
#define QTILES 27       // 1728 / 64
#define NPAIR  (N_TOK / 2)             // 864 fp16 key-pairs per head
#define SCALE  0.70710678118654752f    // 1/sqrt(2)
#define LOG2E  1.44269504088896340736f
#define JW     8                       // waves per attn block (j-split)
#define PCH    (NPAIR / JW)            // 108 key-pairs per wave

typedef _Float16 h2 __attribute__((ext_vector_type(2)));
union H2U { h2 h; unsigned int u; };

__device__ __forceinline__ unsigned int pack2(float a, float b) {
    H2U c; c.h.x = (_Float16)a; c.h.y = (_Float16)b; return c.u;
}
// fp16 dot2 with fp32 accumulator: v_dot2_f32_f16 (1 VALU op)
__device__ __forceinline__ float hdot2a(unsigned int q, unsigned int k, float c) {
    H2U a, b; a.u = q; b.u = k;
#if __has_builtin(__builtin_amdgcn_fdot2)
    return __builtin_amdgcn_fdot2(a.h, b.h, c, false);
#else
    return fmaf((float)a.h.x, (float)b.h.x, fmaf((float)a.h.y, (float)b.h.y, c));
#endif
}
// pack two fp32 -> half2 in one op (v_cvt_pkrtz_f16_f32).
// NOTE: builtin returns __fp16 ext_vector(2) on gfx950 — take it in its
// native type and move the 4 bytes out with memcpy (bit-identical, free).
__device__ __forceinline__ unsigned int pkrtz(float a, float b) {
#if __has_builtin(__builtin_amdgcn_cvt_pkrtz)
    __fp16 r2 __attribute__((ext_vector_type(2))) =
        __builtin_amdgcn_cvt_pkrtz(a, b);
    unsigned int u;
    __builtin_memcpy(&u, &r2, 4);
    return u;
#else
    return pack2(a, b);
#endif
}

// ---- dtype-adaptive load: f32=1 -> fp32 buffer, 0 -> bf16 buffer ----
__device__ __forceinline__ float ldin(const void* p, int i, int f32) {
    if (f32) return ((const float*)p)[i];
    union { unsigned int b; float f; } c;
    c.b = ((unsigned int)((const unsigned short*)p)[i]) << 16;
    return c.f;
}
// ---- wave-local dtype sniff (R1-proven: inputs are fp32 at runtime) ----
__device__ __forceinline__ int sniff_f32(const void* x) {
    union { unsigned int b; float f; } c;
    c.b = ((unsigned int)((const unsigned short*)x)[threadIdx.x & 63]) << 16;
    int bad = (((c.b >> 23) & 0xFF) == 0xFF) || (fabsf(c.f) > 1e10f);
    return (__ballot(bad) != 0ULL) ? 1 : 0;
}

// ========== Kernel 1: QKV -> packed fp16 Q / KV + per-head max|k|^2 ==========
// grid (27, 96), block 64. y -> (h = y&31, which = y>>5 in {q,k,v}).
// KV uint4 layout per pair p: {K(2p)=(k0,k1), K(2p+1)=(k0,k1),
//                              (v0_2p, v0_2p+1), (v1_2p, v1_2p+1)}
// (V pair-transposed via one shfl_xor so attention can dot2-accumulate.)
// K-blocks also wave-reduce max(k0^2+k1^2) -> int atomicMax per head
// (positive-float int ordering; 0xAA ws poison = negative int = free init).
__global__ void __launch_bounds__(64)
qkv_pack(const void* __restrict__ xv, const void* __restrict__ wv,
         unsigned int* __restrict__ Qp, unsigned int* __restrict__ KVg,
         int* __restrict__ Kmax2) {
    const int f     = sniff_f32(xv);
    const int lane  = threadIdx.x;
    const int h     = blockIdx.y & 31;
    const int which = blockIdx.y >> 5;
    const int r0    = (which << 6) + 2 * h;        // uniform -> s_loads
    const int n     = blockIdx.x * 64 + lane;
    float a0 = 0.f, a1 = 0.f;
    if (f) {
        const float* x  = (const float*)xv;
        const float* w0 = (const float*)wv + r0 * CDIM;
        const float* w1 = w0 + CDIM;
#pragma unroll 8
        for (int c = 0; c < CDIM; ++c) {
            float xc = x[c * N_TOK + n];           // coalesced
            a0 = fmaf(xc, w0[c], a0);
            a1 = fmaf(xc, w1[c], a1);
        }
    } else {
#pragma unroll 8
        for (int c = 0; c < CDIM; ++c) {
            float xc = ldin(xv, c * N_TOK + n, 0);
            a0 = fmaf(xc, ldin(wv, r0 * CDIM + c, 0), a0);
            a1 = fmaf(xc, ldin(wv, (r0 + 1) * CDIM + c, 0), a1);
        }
    }
    if (which == 0) {
        Qp[h * N_TOK + n] = pack2(a0 * (SCALE * LOG2E), a1 * (SCALE * LOG2E));
    } else if (which == 1) {
        KVg[(h * NPAIR + (n >> 1)) * 4 + (n & 1)] = pack2(a0, a1);
        float m = fmaf(a0, a0, a1 * a1);           // |k|^2
#pragma unroll
        for (int d = 1; d < 64; d <<= 1) m = fmaxf(m, __shfl_xor(m, d));
        if (lane == 0) atomicMax(Kmax2 + h, __float_as_int(m));
    } else {
        float b0 = __shfl_xor(a0, 1);              // partner v0
        float b1 = __shfl_xor(a1, 1);              // partner v1
        // even lane -> word2 = (v0_even, v0_odd); odd lane -> word3 = (v1_even, v1_odd)
        unsigned int word = (n & 1) ? pack2(b1, a1) : pack2(a0, b0);
        KVg[(h * NPAIR + (n >> 1)) * 4 + 2 + (n & 1)] = word;
    }
}

// ========== Kernel 2: attention — all-dot2 inner loop ==========
// grid (27, 32), block 512 (8 waves). e-weights bounded <=1 by the
// Cauchy-Schwarz shift B = |q'|*max|k| folded into the score-dot2's fp32
// accumulator (B cancels exactly in the softmax ratio). Per uint4 (2 keys):
// 2 score-dot2 + 2 exp2 + 1 cvt_pkrtz + 3 accumulate-dot2 = 6 VALU + 2 trans.
__global__ void __launch_bounds__(512, 4)
attn_kernel(const unsigned int* __restrict__ Qp, const uint4* __restrict__ KVg,
            const int* __restrict__ Kmax2, float* __restrict__ O) {
    __shared__ uint4 KVs[NPAIR];           // 13824 B
    __shared__ float redbuf[JW * 64 * 3];  //  6144 B
    const int tid  = threadIdx.x;
    const int lane = tid & 63;
    const int wav  = tid >> 6;
    const int h    = blockIdx.y;
    const int t0   = blockIdx.x * 64;

    const uint4* src = KVg + h * NPAIR;
    KVs[tid] = src[tid];                               // 512 coalesced b128
    if (tid < NPAIR - 512) KVs[512 + tid] = src[512 + tid];   // +352
    const unsigned int qh = Qp[h * N_TOK + t0 + lane]; // coalesced dword
    // B = |q'| * max|k|  (q' already has SCALE*LOG2E folded in)
    H2U qu; qu.u = qh;
    const float qx = (float)qu.h.x, qy = (float)qu.h.y;
    const float Km = sqrtf(__int_as_float(Kmax2[h]));  // uniform -> scalar
    const float negB = -sqrtf(fmaf(qx, qx, qy * qy)) * Km;
    const unsigned int ones = pack2(1.0f, 1.0f);
    __syncthreads();

    const uint4* KVp = &KVs[wav * PCH];
    float l0 = 0.f, l1 = 0.f, l2 = 0.f, l3 = 0.f;
    float p0 = 0.f, p1 = 0.f, p2 = 0.f, p3 = 0.f;   // o-dim 0 partials
    float s0 = 0.f, s1 = 0.f, s2 = 0.f, s3 = 0.f;   // o-dim 1 partials
#pragma unroll
    for (int g = 0; g < PCH; g += 4) {     // 27 iterations, fully unrolled
        uint4 d0 = KVp[g], d1 = KVp[g + 1], d2 = KVp[g + 2], d3 = KVp[g + 3];
        float ea, eb; unsigned int eh;
        ea = __builtin_amdgcn_exp2f(hdot2a(qh, d0.x, negB));
        eb = __builtin_amdgcn_exp2f(hdot2a(qh, d0.y, negB));
        eh = pkrtz(ea, eb);
        l0 = hdot2a(eh, ones, l0); p0 = hdot2a(eh, d0.z, p0); s0 = hdot2a(eh, d0.w, s0);
        ea = __builtin_amdgcn_exp2f(hdot2a(qh, d1.x, negB));
        eb = __builtin_amdgcn_exp2f(hdot2a(qh, d1.y, negB));
        eh = pkrtz(ea, eb);
        l1 = hdot2a(eh, ones, l1); p1 = hdot2a(eh, d1.z, p1); s1 = hdot2a(eh, d1.w, s1);
        ea = __builtin_amdgcn_exp2f(hdot2a(qh, d2.x, negB));
        eb = __builtin_amdgcn_exp2f(hdot2a(qh, d2.y, negB));
        eh = pkrtz(ea, eb);
        l2 = hdot2a(eh, ones, l2); p2 = hdot2a(eh, d2.z, p2); s2 = hdot2a(eh, d2.w, s2);
        ea = __builtin_amdgcn_exp2f(hdot2a(qh, d3.x, negB));
        eb = __builtin_amdgcn_exp2f(hdot2a(qh, d3.y, negB));
        eh = pkrtz(ea, eb);
        l3 = hdot2a(eh, ones, l3); p3 = hdot2a(eh, d3.z, p3); s3 = hdot2a(eh, d3.w, s3);
    }
    float* red = redbuf + wav * 192 + lane * 3;   // stride-3: <=2-way (free)
    red[0] = (l0 + l1) + (l2 + l3);
    red[1] = (p0 + p1) + (p2 + p3);
    red[2] = (s0 + s1) + (s2 + s3);
    __syncthreads();
    if (wav == 0) {
        float L = 0.f, A = 0.f, B = 0.f;
#pragma unroll
        for (int w = 0; w < JW; ++w) {
            const float* r = redbuf + w * 192 + lane * 3;
            L += r[0]; A += r[1]; B += r[2];
        }
        float inv = 1.0f / L;
        int n = t0 + lane;
        *((float2*)(O + n * CDIM + 2 * h)) = make_float2(A * inv, B * inv);
    }
}

// ========== Kernel 3: output projection (R9-proven, unchanged) ==========
__global__ void __launch_bounds__(256)
proj_kernel(const void* __restrict__ xv,   // dtype sniff only
            const float* __restrict__ O,
            const void* __restrict__ w_proj, const void* __restrict__ b_proj,
            void* __restrict__ out) {
    __shared__ float Ws[CDIM * 65];        // 16640 B
    const int f    = sniff_f32(xv);
    const int tid  = threadIdx.x;
    const int lane = tid & 63;
    const int wav  = tid >> 6;
    for (int e = tid; e < CDIM * CDIM; e += 256)    // e = co*64+ci, coalesced
        Ws[(e & 63) * 65 + (e >> 6)] = ldin(w_proj, e, f);
    __syncthreads();
    int n = blockIdx.x * 4 + wav;          // 432*4 = 1728
    float acc = ldin(b_proj, lane, f);
#pragma unroll 8
    for (int ci = 0; ci < CDIM; ++ci)
        acc = fmaf(O[n * CDIM + ci],                 // uniform -> s_load
                   Ws[ci * 65 + lane], acc);          // bank-conflict-free
    if (f) ((float*)out)[n * CDIM + lane] = acc;
    else   ((__hip_bfloat16*)out)[n * CDIM + lane] = __float2bfloat16(acc);
}

extern "C" void kernel_launch(void* const* d_in, const int* in_sizes, int n_in,
                              void* d_out, int out_size, void* d_ws, size_t ws_size,
                              hipStream_t stream) {
    const void* x      = d_in[0];
    const void* w_qkv  = d_in[1];
    const void* w_proj = d_in[2];
    const void* b_proj = d_in[3];

    // ws layout (~1.11 MB of the proven >=1.77 MB):
    float*        O     = (float*)d_ws;                    // 442368 B [1728][64]
    unsigned int* Qp    = (unsigned int*)(O + N_TOK * CDIM);     // 221184 B
    unsigned int* KVg   = Qp + NHEADS * N_TOK;                   // 442368 B
    int*          Kmax2 = (int*)(KVg + NHEADS * N_TOK * 2);      // 128 B
    // (no memset needed: 0xAA poison = negative int, below any |k|^2 bits)

    qkv_pack   <<<dim3(QTILES, 96), 64, 0, stream>>>(x, w_qkv, Qp, KVg, Kmax2);
    attn_kernel<<<dim3(QTILES, NHEADS), 512, 0, stream>>>(Qp, (const uint4*)KVg,
                                                          Kmax2, O);
    proj_kernel<<<432, 256, 0, stream>>>(x, O, w_proj, b_proj, d_out);
}